// Round 3
// baseline (698.902 us; speedup 1.0000x reference)
//
#include <hip/hip_runtime.h>
#include <math.h>

#define B_  128
#define C_  512
#define S_  128
#define M_  512
#define BN_EPS 1e-5f

typedef __attribute__((ext_vector_type(8))) short   short8;
typedef __attribute__((ext_vector_type(4))) float   floatx4;
typedef __attribute__((ext_vector_type(4))) unsigned short ushort4v;

// fp32 -> bf16 bits, round-to-nearest-even (finite inputs)
__device__ __forceinline__ unsigned short f2bu(float f) {
    union { float f; unsigned int u; } c; c.f = f;
    unsigned int u = c.u;
    return (unsigned short)((u + 0x7fffu + ((u >> 16) & 1u)) >> 16);
}

// async global->LDS, 16 bytes per lane; lds dest = wave-uniform base + lane*16
__device__ __forceinline__ void gload_lds16(const unsigned short* g, unsigned short* l)
{
    __builtin_amdgcn_global_load_lds(
        (const __attribute__((address_space(1))) unsigned int*)g,
        (__attribute__((address_space(3))) unsigned int*)l,
        16, 0, 0);
}

// ---------------------------------------------------------------------------
// fp32 -> bf16: q,k,v in one launch (blockIdx.y selects tensor)
// ---------------------------------------------------------------------------
__global__ __launch_bounds__(256)
void f2bf3_kernel(const float* __restrict__ q, const float* __restrict__ k,
                  const float* __restrict__ v,
                  unsigned short* __restrict__ qo, unsigned short* __restrict__ ko,
                  unsigned short* __restrict__ vo)
{
    const long i = (long)blockIdx.x * 256 + threadIdx.x;   // 8-elem groups
    const float* in; unsigned short* out;
    if (blockIdx.y == 0)      { in = q; out = qo; }
    else if (blockIdx.y == 1) { in = k; out = ko; }
    else                      { in = v; out = vo; }
    const float4* p = (const float4*)in + 2 * i;
    const float4 x = p[0], y = p[1];
    ushort4v u0, u1;
    u0.x = f2bu(x.x); u0.y = f2bu(x.y); u0.z = f2bu(x.z); u0.w = f2bu(x.w);
    u1.x = f2bu(y.x); u1.y = f2bu(y.y); u1.z = f2bu(y.z); u1.w = f2bu(y.w);
    ((ushort4v*)out)[2 * i]     = u0;
    ((ushort4v*)out)[2 * i + 1] = u1;
}

// weights: 4 matrices of 65536 elements each (blockIdx.y selects)
__global__ __launch_bounds__(256)
void f2bfw_kernel(const float* __restrict__ w0, const float* __restrict__ w1,
                  const float* __restrict__ w2, const float* __restrict__ w3,
                  unsigned short* __restrict__ o0, unsigned short* __restrict__ o1,
                  unsigned short* __restrict__ o2, unsigned short* __restrict__ o3)
{
    const long i = (long)blockIdx.x * 256 + threadIdx.x;
    const float* in; unsigned short* out;
    if (blockIdx.y == 0)      { in = w0; out = o0; }
    else if (blockIdx.y == 1) { in = w1; out = o1; }
    else if (blockIdx.y == 2) { in = w2; out = o2; }
    else                      { in = w3; out = o3; }
    const float4* p = (const float4*)in + 2 * i;
    const float4 x = p[0], y = p[1];
    ushort4v u0, u1;
    u0.x = f2bu(x.x); u0.y = f2bu(x.y); u0.z = f2bu(x.z); u0.w = f2bu(x.w);
    u1.x = f2bu(y.x); u1.y = f2bu(y.y); u1.z = f2bu(y.z); u1.w = f2bu(y.w);
    ((ushort4v*)out)[2 * i]     = u0;
    ((ushort4v*)out)[2 * i + 1] = u1;
}

// ---------------------------------------------------------------------------
// bf16 MFMA GEMM, NT: C[i,j] = scale*sum_k A[i,k]*Bm[j,k] (+bias)
// BM=BN=128, BK=64, 256 thr (4 waves 2x2, 64x64/wave, 4x4 frags 16x16x32).
// global_load_lds staging, XOR-swizzled LDS (8 granules/row of 16B).
// outMode 0: fp32 C; 1: bf16 C.  biasRow: bias indexed by row instead of col.
// All dims divide tiles exactly.
// ---------------------------------------------------------------------------
__global__ __launch_bounds__(256, 4)
void gemm_bf16(const unsigned short* __restrict__ A,
               const unsigned short* __restrict__ Bm,
               const float* __restrict__ bias, void* __restrict__ Cc,
               int K, int ldA, int ldB, int ldC,
               long sA, long sB, long sC, float scale,
               int outMode, int biasRow)
{
    const int bz = blockIdx.z;
    A  += (long)bz * sA;
    Bm += (long)bz * sB;

    __shared__ __attribute__((aligned(16))) unsigned short As[128 * 64];
    __shared__ __attribute__((aligned(16))) unsigned short Bs[128 * 64];

    const int t    = threadIdx.x;
    const int lane = t & 63;
    const int wave = t >> 6;
    const int wm   = (wave >> 1) * 64;
    const int wn   = (wave & 1) * 64;
    const int lrow = lane & 15;
    const int quad = lane >> 4;
    const int row0 = blockIdx.x * 128;
    const int col0 = blockIdx.y * 128;

    // staging: granule (16B) index g = wave*256 + i*64 + lane
    // row = g>>3, phys col-granule = g&7, logical cg = (g&7) ^ (row&7)
    const int slr = lane >> 3;              // row-within-8
    const int scg = (lane & 7) ^ slr;       // logical col granule to fetch

    floatx4 acc[4][4] = {};

    for (int k0 = 0; k0 < K; k0 += 64) {
        #pragma unroll
        for (int i = 0; i < 4; ++i) {
            const int r = wave * 32 + i * 8 + slr;
            gload_lds16(A  + (long)(row0 + r) * ldA + k0 + scg * 8,
                        As + (wave * 256 + i * 64) * 8);
            gload_lds16(Bm + (long)(col0 + r) * ldB + k0 + scg * 8,
                        Bs + (wave * 256 + i * 64) * 8);
        }
        __syncthreads();

        #pragma unroll
        for (int kb = 0; kb < 2; ++kb) {
            short8 af[4];
            #pragma unroll
            for (int i = 0; i < 4; ++i) {
                const int r  = wm + i * 16 + lrow;
                const int pg = r * 8 + ((kb * 4 + quad) ^ (r & 7));
                af[i] = *(const short8*)(As + pg * 8);
            }
            #pragma unroll
            for (int j = 0; j < 4; ++j) {
                const int r  = wn + j * 16 + lrow;
                const int pg = r * 8 + ((kb * 4 + quad) ^ (r & 7));
                const short8 bf8 = *(const short8*)(Bs + pg * 8);
                #pragma unroll
                for (int i = 0; i < 4; ++i)
                    acc[i][j] = __builtin_amdgcn_mfma_f32_16x16x32_bf16(
                        af[i], bf8, acc[i][j], 0, 0, 0);
            }
        }
        __syncthreads();
    }

    // epilogue. C/D layout: col=lane&15, row=quad*4+reg
    #pragma unroll
    for (int j = 0; j < 4; ++j) {
        const int col = col0 + wn + j * 16 + lrow;
        #pragma unroll
        for (int i = 0; i < 4; ++i) {
            const int rbase = row0 + wm + i * 16 + quad * 4;
            #pragma unroll
            for (int reg = 0; reg < 4; ++reg) {
                const int r = rbase + reg;
                float v = acc[i][j][reg] * scale;
                if (bias) v += biasRow ? bias[r] : bias[col];
                if (outMode == 0)
                    ((float*)Cc)[(long)bz * sC + (long)r * ldC + col] = v;
                else
                    ((unsigned short*)Cc)[(long)bz * sC + (long)r * ldC + col] = f2bu(v);
            }
        }
    }
}

// ---------------------------------------------------------------------------
// Fused scores + softmax: block = 128 q-rows x ALL 512 k-cols for one batch.
// 1024 thr = 16 waves (2 row x 8 col of 64x64 tiles). BK=32.
// Writes normalized fp32 attention (output 1) + bf16 copy. Nothing else.
// LDS: Qs 8KB + Ks 32KB + red 4KB = 44KB.
// ---------------------------------------------------------------------------
__global__ __launch_bounds__(1024, 4)
void scores_softmax(const unsigned short* __restrict__ Q,
                    const unsigned short* __restrict__ Kb,
                    float* __restrict__ attn, unsigned short* __restrict__ attnbf,
                    float scale)
{
    const int b    = blockIdx.y;
    const int row0 = blockIdx.x * 128;
    Q      += ((long)b * C_ + row0) * M_;
    Kb     += (long)b * C_ * M_;
    attn   += (long)b * C_ * C_;
    attnbf += (long)b * C_ * C_;

    __shared__ __attribute__((aligned(16))) unsigned short Qs[128 * 32];
    __shared__ __attribute__((aligned(16))) unsigned short Ks[512 * 32];
    __shared__ float red[128][8];

    const int t    = threadIdx.x;
    const int lane = t & 63;
    const int wave = t >> 6;       // 0..15
    const int wr   = wave >> 3;    // 0..1  (row half)
    const int wc   = wave & 7;     // 0..7  (col eighth)
    const int lrow = lane & 15;
    const int quad = lane >> 4;

    // staging swizzle, 4 granules/row (BK=32): g = idx*64 + lane,
    // row = g>>2, cg = (g&3) ^ (row&3)
    const int slr = lane >> 2;                   // row-within-16
    const int scg = (lane & 3) ^ (slr & 3);

    floatx4 acc[4][4] = {};

    for (int k0 = 0; k0 < M_; k0 += 32) {
        // K tile: 32 instrs, wave w handles {2w, 2w+1}
        #pragma unroll
        for (int ii = 0; ii < 2; ++ii) {
            const int idx = wave * 2 + ii;
            const int r   = idx * 16 + slr;            // 0..511
            gload_lds16(Kb + (long)r * M_ + k0 + scg * 8,
                        Ks + idx * 512);               // idx*64 granules *8 shorts
        }
        // Q tile: 8 instrs, waves 0..7
        if (wave < 8) {
            const int r = wave * 16 + slr;             // 0..127
            gload_lds16(Q + (long)r * M_ + k0 + scg * 8,
                        Qs + wave * 512);
        }
        __syncthreads();

        short8 af[4];
        #pragma unroll
        for (int i = 0; i < 4; ++i) {
            const int r  = wr * 64 + i * 16 + lrow;
            const int pg = r * 4 + (quad ^ (r & 3));
            af[i] = *(const short8*)(Qs + pg * 8);
        }
        #pragma unroll
        for (int j = 0; j < 4; ++j) {
            const int r  = wc * 64 + j * 16 + lrow;
            const int pg = r * 4 + (quad ^ (r & 3));
            const short8 bf8 = *(const short8*)(Ks + pg * 8);
            #pragma unroll
            for (int i = 0; i < 4; ++i)
                acc[i][j] = __builtin_amdgcn_mfma_f32_16x16x32_bf16(
                    af[i], bf8, acc[i][j], 0, 0, 0);
        }
        __syncthreads();
    }

    // ---- softmax over each row (raw scores; scale folded into exp) ----
    // 1. partial max over this wave's 64 cols -> red[row][wc]
    #pragma unroll
    for (int i = 0; i < 4; ++i)
        #pragma unroll
        for (int reg = 0; reg < 4; ++reg) {
            float m = fmaxf(fmaxf(acc[i][0][reg], acc[i][1][reg]),
                            fmaxf(acc[i][2][reg], acc[i][3][reg]));
            #pragma unroll
            for (int off = 1; off < 16; off <<= 1)
                m = fmaxf(m, __shfl_xor(m, off));
            if (lrow == 0)
                red[wr * 64 + i * 16 + quad * 4 + reg][wc] = m;
        }
    __syncthreads();

    // 2. combine 8 partials -> full row max
    float mrow[4][4];
    #pragma unroll
    for (int i = 0; i < 4; ++i)
        #pragma unroll
        for (int reg = 0; reg < 4; ++reg) {
            const int r = wr * 64 + i * 16 + quad * 4 + reg;
            const float4 a = *(const float4*)&red[r][0];
            const float4 b = *(const float4*)&red[r][4];
            mrow[i][reg] = fmaxf(fmaxf(fmaxf(a.x, a.y), fmaxf(a.z, a.w)),
                                 fmaxf(fmaxf(b.x, b.y), fmaxf(b.z, b.w)));
        }
    __syncthreads();   // everyone done reading maxes before red is reused

    // 3. exp (in place) + partial sums -> red[row][wc]
    const float c2 = scale * 1.44269504088896f;   // scale * log2(e)
    #pragma unroll
    for (int i = 0; i < 4; ++i)
        #pragma unroll
        for (int reg = 0; reg < 4; ++reg) {
            float s = 0.f;
            #pragma unroll
            for (int j = 0; j < 4; ++j) {
                const float e = exp2f((acc[i][j][reg] - mrow[i][reg]) * c2);
                acc[i][j][reg] = e;
                s += e;
            }
            #pragma unroll
            for (int off = 1; off < 16; off <<= 1)
                s += __shfl_xor(s, off);
            if (lrow == 0)
                red[wr * 64 + i * 16 + quad * 4 + reg][wc] = s;
        }
    __syncthreads();

    // 4. combine sums, normalize, store fp32 + bf16
    #pragma unroll
    for (int i = 0; i < 4; ++i)
        #pragma unroll
        for (int reg = 0; reg < 4; ++reg) {
            const int rl = wr * 64 + i * 16 + quad * 4 + reg;
            const float4 a = *(const float4*)&red[rl][0];
            const float4 b = *(const float4*)&red[rl][4];
            const float sum = (a.x + a.y + a.z + a.w) + (b.x + b.y + b.z + b.w);
            const float inv = 1.0f / sum;
            const long rowoff = (long)(row0 + rl) * C_;
            #pragma unroll
            for (int j = 0; j < 4; ++j) {
                const int col = wc * 64 + j * 16 + lrow;
                const float v = acc[i][j][reg] * inv;
                attn[rowoff + col]   = v;
                attnbf[rowoff + col] = f2bu(v);
            }
        }
}

// ---------------------------------------------------------------------------
// BatchNorm stats: one block per channel, reduce over (b, s)
// ---------------------------------------------------------------------------
__global__ __launch_bounds__(256)
void bn_stats_kernel(const float* __restrict__ outp, float* __restrict__ stats)
{
    const int c   = blockIdx.x;
    const int tid = threadIdx.x;
    float s = 0.f, ss = 0.f;
    for (int idx = tid; idx < B_ * S_; idx += 256) {
        const int b  = idx >> 7;
        const int sp = idx & 127;
        const float x = outp[((long)b * C_ + c) * S_ + sp];
        s  += x;
        ss += x * x;
    }
    __shared__ float shs[256];
    __shared__ float shss[256];
    shs[tid] = s; shss[tid] = ss;
    __syncthreads();
    for (int off = 128; off > 0; off >>= 1) {
        if (tid < off) { shs[tid] += shs[tid + off]; shss[tid] += shss[tid + off]; }
        __syncthreads();
    }
    if (tid == 0) {
        const float n    = (float)(B_ * S_);
        const float mean = shs[0] / n;
        const float var  = shss[0] / n - mean * mean;
        stats[c]      = mean;
        stats[C_ + c] = rsqrtf(var + BN_EPS);
    }
}

// ---------------------------------------------------------------------------
// BN + ReLU + residual
// ---------------------------------------------------------------------------
__global__ __launch_bounds__(256)
void bn_apply_kernel(const float* __restrict__ outp, const float* __restrict__ value,
                     const float* __restrict__ stats, const float* __restrict__ gamma,
                     const float* __restrict__ beta, float* __restrict__ out)
{
    const long i4 = (long)blockIdx.x * 256 + threadIdx.x;
    const int  c  = (int)((i4 >> 5) & (C_ - 1));

    const float mean = stats[c];
    const float istd = stats[C_ + c];
    const float g    = gamma[c] * istd;
    const float bc   = beta[c] - mean * g;

    const float4 x = ((const float4*)outp)[i4];
    const float4 r = ((const float4*)value)[i4];
    float4 y;
    y.x = fmaxf(fmaf(x.x, g, bc), 0.f) + r.x;
    y.y = fmaxf(fmaf(x.y, g, bc), 0.f) + r.y;
    y.z = fmaxf(fmaf(x.z, g, bc), 0.f) + r.z;
    y.w = fmaxf(fmaf(x.w, g, bc), 0.f) + r.w;
    ((float4*)out)[i4] = y;
}

// ---------------------------------------------------------------------------
extern "C" void kernel_launch(void* const* d_in, const int* in_sizes, int n_in,
                              void* d_out, int out_size, void* d_ws, size_t ws_size,
                              hipStream_t stream)
{
    const float* query = (const float*)d_in[0];
    const float* key   = (const float*)d_in[1];
    const float* value = (const float*)d_in[2];
    const float* Wq    = (const float*)d_in[3];
    const float* bq    = (const float*)d_in[4];
    const float* Wk    = (const float*)d_in[5];
    const float* bk    = (const float*)d_in[6];
    const float* Wv    = (const float*)d_in[7];
    const float* bv    = (const float*)d_in[8];
    const float* Wf    = (const float*)d_in[9];
    const float* bf    = (const float*)d_in[10];
    const float* gamma = (const float*)d_in[11];
    const float* beta  = (const float*)d_in[12];

    const long BC  = (long)B_ * C_;       // 65536
    const long BCM = BC * M_;             // 33,554,432
    const long BCS = BC * S_;             //  8,388,608
    const long BCC = BC * C_;             // 33,554,432

    // ---- workspace carve (bf16 = ushort), 16B-aligned offsets
    unsigned short* w      = (unsigned short*)d_ws;
    unsigned short* q_bf   = w;                     // [BC, M]
    unsigned short* k_bf   = q_bf + BCM;            // [BC, M]
    unsigned short* v2_bf  = k_bf + BCM;            // [BC, M]
    unsigned short* attnbf = v2_bf + BCM;           // [B, C, C]
    unsigned short* vwT    = attnbf + BCC;          // [S, B*C] = [128, 65536]
    unsigned short* qin    = vwT + BCS;             // [BC, S]
    unsigned short* kin    = qin + BCS;
    unsigned short* vin    = kin + BCS;
    unsigned short* Wq_bf  = vin + BCS;             // [M, S]
    unsigned short* Wk_bf  = Wq_bf + (long)M_ * S_;
    unsigned short* Wv_bf  = Wk_bf + (long)M_ * S_;
    unsigned short* Wf_bf  = Wv_bf + (long)M_ * S_; // [S, M]
    float* outp  = (float*)(Wf_bf + (long)S_ * M_); // [BC, S] fp32
    float* stats = outp + BCS;                      // [2*C]

    float* out0 = (float*)d_out;          // [B, C, S]
    float* attn = out0 + BCS;             // [B, C, C]

    const float scale = 1.0f / sqrtf((float)M_);
    dim3 blk(256);

    // 0. fp32 -> bf16
    f2bf3_kernel<<<dim3(BCS / 8 / 256, 3), blk, 0, stream>>>(
        query, key, value, qin, kin, vin);
    f2bfw_kernel<<<dim3(32, 4), blk, 0, stream>>>(
        Wq, Wk, Wv, Wf, Wq_bf, Wk_bf, Wv_bf, Wf_bf);

    // 1. projections: [BC,S] x [M,S]^T -> bf16 [BC,M]
    gemm_bf16<<<dim3(512, 4, 1), blk, 0, stream>>>(
        qin, Wq_bf, bq, q_bf,  S_, S_, S_, M_, 0, 0, 0, 1.0f, 1, 0);
    gemm_bf16<<<dim3(512, 4, 1), blk, 0, stream>>>(
        kin, Wk_bf, bk, k_bf,  S_, S_, S_, M_, 0, 0, 0, 1.0f, 1, 0);
    gemm_bf16<<<dim3(512, 4, 1), blk, 0, stream>>>(
        vin, Wv_bf, bv, v2_bf, S_, S_, S_, M_, 0, 0, 0, 1.0f, 1, 0);

    // 2+3. fused scores + softmax -> attn fp32 (output 1) + attnbf
    scores_softmax<<<dim3(C_ / 128, B_), dim3(1024), 0, stream>>>(
        q_bf, k_bf, attn, attnbf, scale);

    // 4. vwT = Wf @ v2^T (+bf per row): [S,M] x [BC,M]^T -> [S, BC] bf16
    //    (bias fold exact: softmax rows sum to 1)
    gemm_bf16<<<dim3(1, 512, 1), blk, 0, stream>>>(
        Wf_bf, v2_bf, bf, vwT, M_, M_, M_, (int)BC, 0, 0, 0, 1.0f, 1, 1);

    // 5. outp = attn @ vw (NT via vwT): per batch [C,C] x [S, C]^T -> [C,S]
    gemm_bf16<<<dim3(C_ / 128, 1, B_), blk, 0, stream>>>(
        attnbf, vwT, nullptr, outp, C_, C_, (int)BC, S_,
        (long)C_ * C_, (long)C_, (long)C_ * S_, 1.0f, 0, 0);

    // 6. BN stats
    bn_stats_kernel<<<dim3(C_), blk, 0, stream>>>(outp, stats);

    // 7. BN + ReLU + residual -> out0
    bn_apply_kernel<<<dim3(BCS / 4 / 256), blk, 0, stream>>>(
        outp, value, stats, gamma, beta, out0);
}